// Round 2
// baseline (232.978 us; speedup 1.0000x reference)
//
#include <hip/hip_runtime.h>
#include <hip/hip_bf16.h>

typedef __bf16 bf16x8 __attribute__((ext_vector_type(8)));
typedef float f32x4 __attribute__((ext_vector_type(4)));
typedef float f32x16 __attribute__((ext_vector_type(16)));
typedef unsigned short u16;
typedef unsigned int u32;

__device__ __forceinline__ u16 f2bf_rne(float f){
  union { float f; u32 u; } v; v.f = f;
  u32 r = v.u + 0x7fffu + ((v.u >> 16) & 1u);
  return (u16)(r >> 16);
}
// pack hi16(a)|hi16(b)<<16 in ONE v_perm_b32 (truncation; P feeds attention weights)
__device__ __forceinline__ u32 pack2(float a, float b){
  return __builtin_amdgcn_perm(__float_as_uint(a), __float_as_uint(b), 0x03020706u);
}
// workgroup barrier WITHOUT vmcnt drain (LDS visibility only): in-flight global
// loads (K/V register prefetches) ride through; compiler vmcnt-waits at use.
#define BARRIER_LGKM() asm volatile("s_waitcnt lgkmcnt(0)\n\ts_barrier" ::: "memory")

// ------------- prep: Wfrag = [Wh|Wf|Wg]^T in MFMA B-fragment order -------------
// Wfrag[cc(20)][kk(8)][lane(64)][j(8)] bf16; lane=(quad,L):
//   element = Wcat[k = kk*32 + quad*8 + j][n = cc*16 + L]
__global__ __launch_bounds__(512) void prep_kernel(
    const float* __restrict__ Wf, const float* __restrict__ Wg,
    const float* __restrict__ Wh, u16* __restrict__ Wfrag){
  const int cc = blockIdx.x;             // 20
  const int t = threadIdx.x;             // 512 = kk(8) x lane(64)
  const int kk = t >> 6, lane = t & 63;
  const int L = lane & 15, quad = lane >> 4;
  const int n = cc * 16 + L;
  u32 pk[4];
  #pragma unroll
  for (int j2 = 0; j2 < 4; ++j2){
    float v[2];
    #pragma unroll
    for (int h = 0; h < 2; ++h){
      int k = kk * 32 + quad * 8 + j2 * 2 + h;
      if (n < 256)      v[h] = Wh[k * 256 + n];
      else if (n < 288) v[h] = Wf[k * 32 + (n - 256)];
      else              v[h] = Wg[k * 32 + (n - 288)];
    }
    pk[j2] = (u32)f2bf_rne(v[0]) | ((u32)f2bf_rne(v[1]) << 16);
  }
  uint4* dst = (uint4*)(Wfrag + ((size_t)(cc * 8 + kk) * 64 + lane) * 8);
  *dst = make_uint4(pk[0], pk[1], pk[2], pk[3]);
}

// ---------------- projection: h/f/g via MFMA, 512 thr / 8 waves ----------------
// Qg pre-scaled by log2(e). V emitted fragment-major per 64-row group:
// Vfrag[g64][p_hi(8)][c(256)][j(8)], p = ((tn&15)<<2)|(tn>>4).
__global__ __launch_bounds__(512) void proj_kernel(
    const float* __restrict__ x, const u16* __restrict__ Wfrag,
    u16* __restrict__ Qg, u16* __restrict__ Kg, u16* __restrict__ Vfrag)
{
  __shared__ __align__(16) u16 smem[256 * 72];   // 36 KB, two phases
  u16 (*xb)[264] = (u16(*)[264])smem;
  u16 (*Vr)[72]  = (u16(*)[72])smem;

  const int tid = threadIdx.x;
  const int lane = tid & 63, wave = tid >> 6;
  const int L = lane & 15, quad = lane >> 4;
  const int rowgrp = wave >> 1, colhalf = wave & 1;
  const int n0 = blockIdx.x * 64;

  const float4* xsrc = (const float4*)(x + (size_t)n0 * 256);
  #pragma unroll
  for (int j = 0; j < 8; ++j){
    int idx = j * 512 + tid;
    int row = idx >> 6, col4 = idx & 63;
    float4 v = xsrc[idx];
    u32 p0 = (u32)f2bf_rne(v.x) | ((u32)f2bf_rne(v.y) << 16);
    u32 p1 = (u32)f2bf_rne(v.z) | ((u32)f2bf_rne(v.w) << 16);
    *(uint2*)&xb[row][col4 * 4] = make_uint2(p0, p1);
  }
  __syncthreads();

  f32x4 acc[10];
  #pragma unroll
  for (int cc = 0; cc < 10; ++cc) acc[cc] = (f32x4){0.f, 0.f, 0.f, 0.f};

  #pragma unroll
  for (int kk = 0; kk < 8; ++kk){
    bf16x8 a = *(const bf16x8*)&xb[rowgrp * 16 + L][kk * 32 + quad * 8];
    #pragma unroll
    for (int cc = 0; cc < 10; ++cc){
      int ccg = colhalf * 10 + cc;
      bf16x8 bfr = *(const bf16x8*)(Wfrag + ((size_t)(ccg * 8 + kk) * 64 + lane) * 8);
      acc[cc] = __builtin_amdgcn_mfma_f32_16x16x32_bf16(a, bfr, acc[cc], 0, 0, 0);
    }
  }

  if (colhalf){
    #pragma unroll
    for (int cc = 6; cc < 10; ++cc){
      int ccg = 10 + cc;                                  // 16..19
      u16* dst = (ccg < 18) ? Kg : Qg;                    // K = f, Q = g
      float sc = (ccg < 18) ? 1.0f : 1.44269504088896f;
      int c = (ccg & 1) * 16 + L;
      #pragma unroll
      for (int r = 0; r < 4; ++r){
        int row = n0 + rowgrp * 16 + quad * 4 + r;
        dst[(size_t)row * 32 + c] = f2bf_rne(acc[cc][r] * sc);
      }
    }
  }

  __syncthreads();   // xb consumed; reuse smem as Vr

  {
    const int cmax = colhalf ? 6 : 10;
    for (int cc = 0; cc < cmax; ++cc){
      int ccg = colhalf * 10 + cc;
      int c = ccg * 16 + L;
      #pragma unroll
      for (int r = 0; r < 4; ++r){
        int tn = rowgrp * 16 + quad * 4 + r;
        int p  = ((tn & 15) << 2) | (tn >> 4);
        Vr[c][p] = f2bf_rne(acc[cc][r]);
      }
    }
  }
  __syncthreads();

  u16* Vblk = Vfrag + (size_t)blockIdx.x * (256 * 64);
  #pragma unroll
  for (int i = 0; i < 4; ++i){
    int idx = i * 512 + tid;
    *(uint4*)(Vblk + (size_t)idx * 8) = *(const uint4*)&Vr[idx & 255][(idx >> 8) * 8];
  }
}

// ------- flash: q-tile 64, 16 waves = 4 internal k-quarters, fused epilogue ----
// grid 256 x 1024 thr, 1 block/CU, 16 waves/CU = 4 waves/SIMD (2x R1's TLP).
// quarter = wave>>2 sweeps k in [quarter*1024, +1024) (16 groups of 64) with its
// own double-buffered Plds; wv = wave&3. Same per-tile work/layouts as the
// 2-half version (QK: wave = 16 q-rows x 64 k, 4 MFMA; PV: wave = 64q x 64c,
// vf in regs). K/V traffic per block UNCHANGED (each quarter reads only its own
// k-range; each V tile read once per block). This is a pure occupancy lever:
// R1 proved instruction-order pipelining is not the limiter (MfmaUtil 27->27);
// counters (both pipes <30%, Occupancy 18%) say latency-bound at 2 waves/SIMD.
// Epilogue: 4 quarters merge sequentially via LDS Osh (overlays Plds), l via
// Lsh, then out = gamma*O/l + x written fully coalesced.
__global__ __launch_bounds__(1024) void flash_kernel(
    const u16* __restrict__ Qg, const u16* __restrict__ Kg, const u16* __restrict__ Vfrag,
    const float* __restrict__ x, const float* __restrict__ gamma, float* __restrict__ out)
{
  constexpr float SH = -92.33248261689366f;      // -64*log2(e); s already log2-scaled
  __shared__ __align__(16) char smem[73728];     // Plds 73728 B overlaid by Osh 64 KB
  u16 (*Plds)[2][64][72] = (u16 (*)[2][64][72])smem;  // [quarter][buf][row][72]
  float (*Osh)[256] = (float (*)[256])smem;
  __shared__ float Lsh[4][64];

  const int tid = threadIdx.x, lane = tid & 63, wave = tid >> 6;   // wave 0..15
  const int L = lane & 15, quad = lane >> 4;
  const int m32 = lane & 31, h32 = lane >> 5;
  const int quarter = wave >> 2, wv = wave & 3;

  // XCD swizzle: id&7 -> XCD; 2 XCDs per batch (V+K+Q working set ~2.5MB < 4MB L2)
  const int id = blockIdx.x;                     // 0..255
  const int xcd = id & 7;
  const int b = xcd >> 1;
  const int qt = (xcd & 1) * 32 + (id >> 3);     // 0..63
  const int q0 = qt * 64;

  const u16* Qb = Qg + (size_t)(b * 4096) * 32;
  const u16* Kb = Kg + (size_t)(b * 4096) * 32;
  const u16* Vb = Vfrag + (size_t)b * (64 * 256 * 64);
  const float gm = gamma[0];

  const int g0 = quarter * 16;                   // 16 k-tiles per quarter

  bf16x8 qa = *(const bf16x8*)(Qb + (size_t)(q0 + wv * 16 + L) * 32 + quad * 8);
  const u16* kp0 = Kb + (size_t)(g0 * 64 + L) * 32 + quad * 8;
  bf16x8 kc0 = *(const bf16x8*)(kp0);
  bf16x8 kc1 = *(const bf16x8*)(kp0 + 512);
  bf16x8 kc2 = *(const bf16x8*)(kp0 + 1024);
  bf16x8 kc3 = *(const bf16x8*)(kp0 + 1536);

  bf16x8 vfc[8];
  {
    const u16* Vt = Vb + (size_t)g0 * (256 * 64);
    #pragma unroll
    for (int ks = 0; ks < 4; ++ks){
      const u16* vrow = Vt + (size_t)((ks * 2 + h32) * 256 + wv * 64 + m32) * 8;
      vfc[ks * 2]     = *(const bf16x8*)(vrow);
      vfc[ks * 2 + 1] = *(const bf16x8*)(vrow + 32 * 8);
    }
  }

  f32x16 acc[4];                                  // [qi*2+ci]: 64q x 64c
  #pragma unroll
  for (int t = 0; t < 4; ++t)
    #pragma unroll
    for (int i = 0; i < 16; ++i) acc[t][i] = 0.f;
  float lsum[4] = {0.f, 0.f, 0.f, 0.f};
  const f32x4 zero = (f32x4){0.f, 0.f, 0.f, 0.f};

  for (int kt = 0; kt < 16; ++kt){
    const int g = g0 + kt;
    u16 (*Pw)[72] = Plds[quarter][kt & 1];

    // ---- QK^T from registers (s log2-scaled via Qg) ----
    f32x4 s0 = __builtin_amdgcn_mfma_f32_16x16x32_bf16(qa, kc0, zero, 0, 0, 0);
    f32x4 s1 = __builtin_amdgcn_mfma_f32_16x16x32_bf16(qa, kc1, zero, 0, 0, 0);
    f32x4 s2 = __builtin_amdgcn_mfma_f32_16x16x32_bf16(qa, kc2, zero, 0, 0, 0);
    f32x4 s3 = __builtin_amdgcn_mfma_f32_16x16x32_bf16(qa, kc3, zero, 0, 0, 0);

    // ---- kc reload for kt+1 (window = exp + barrier + PV) ----
    if (kt < 15){
      const u16* kpn = Kb + (size_t)((g + 1) * 64 + L) * 32 + quad * 8;
      kc0 = *(const bf16x8*)(kpn);
      kc1 = *(const bf16x8*)(kpn + 512);
      kc2 = *(const bf16x8*)(kpn + 1024);
      kc3 = *(const bf16x8*)(kpn + 1536);
    }

    // ---- p = exp2(s+SH); lsum; packed P store (col' = L*4+j) ----
    #pragma unroll
    for (int r = 0; r < 4; ++r){
      float p0 = __builtin_amdgcn_exp2f(s0[r] + SH);
      float p1 = __builtin_amdgcn_exp2f(s1[r] + SH);
      float p2 = __builtin_amdgcn_exp2f(s2[r] + SH);
      float p3 = __builtin_amdgcn_exp2f(s3[r] + SH);
      lsum[r] += (p0 + p1) + (p2 + p3);
      *(uint2*)&Pw[wv * 16 + quad * 4 + r][L * 4] =
          make_uint2(pack2(p0, p1), pack2(p2, p3));
    }

    BARRIER_LGKM();   // P visible; global prefetches ride through

    // ---- O += P V : af from own quarter's Plds, vf already in registers ----
    #pragma unroll
    for (int ks = 0; ks < 4; ++ks){
      bf16x8 af0 = *(const bf16x8*)&Pw[m32][ks * 16 + h32 * 8];
      bf16x8 af1 = *(const bf16x8*)&Pw[32 + m32][ks * 16 + h32 * 8];
      acc[0] = __builtin_amdgcn_mfma_f32_32x32x16_bf16(af0, vfc[ks*2],   acc[0], 0, 0, 0);
      acc[1] = __builtin_amdgcn_mfma_f32_32x32x16_bf16(af0, vfc[ks*2+1], acc[1], 0, 0, 0);
      acc[2] = __builtin_amdgcn_mfma_f32_32x32x16_bf16(af1, vfc[ks*2],   acc[2], 0, 0, 0);
      acc[3] = __builtin_amdgcn_mfma_f32_32x32x16_bf16(af1, vfc[ks*2+1], acc[3], 0, 0, 0);
    }

    // ---- vf loads for kt+1 into the same regs (consumed after next barrier) ----
    if (kt < 15){
      const u16* Vn = Vb + (size_t)(g + 1) * (256 * 64);
      #pragma unroll
      for (int ks = 0; ks < 4; ++ks){
        const u16* vrow = Vn + (size_t)((ks * 2 + h32) * 256 + wv * 64 + m32) * 8;
        vfc[ks * 2]     = *(const bf16x8*)(vrow);
        vfc[ks * 2 + 1] = *(const bf16x8*)(vrow + 32 * 8);
      }
    }
    // no end barrier: per-quarter Plds double-buffered; reuse gated by next barrier
  }

  // ================= fused epilogue (4-way k-quarter merge) =================
  // l: reduce 16 partial lanes per (quad,r); rows wv*16+quad*4+r of this quarter
  #pragma unroll
  for (int r = 0; r < 4; ++r){
    lsum[r] += __shfl_xor(lsum[r], 1);
    lsum[r] += __shfl_xor(lsum[r], 2);
    lsum[r] += __shfl_xor(lsum[r], 4);
    lsum[r] += __shfl_xor(lsum[r], 8);
  }
  if (L == 0){
    #pragma unroll
    for (int r = 0; r < 4; ++r) Lsh[quarter][wv * 16 + quad * 4 + r] = lsum[r];
  }

  BARRIER_LGKM();   // all PV ds-reads retired (per-wave lgkm drain) + Lsh visible

  // quarter 3 deposits its accumulator into Osh (fp32); wave 0 computes scale
  if (quarter == 3){
    #pragma unroll
    for (int t = 0; t < 4; ++t){
      const int qi = t >> 1, ci = t & 1;
      #pragma unroll
      for (int rg = 0; rg < 16; ++rg){
        int row = qi * 32 + (rg & 3) + 8 * (rg >> 2) + 4 * h32;   // 32x32 C-layout
        Osh[row][wv * 64 + ci * 32 + m32] = acc[t][rg];
      }
    }
  }
  float li_w0 = 0.f;
  if (wave == 0)
    li_w0 = gm / (Lsh[0][lane] + Lsh[1][lane] + Lsh[2][lane] + Lsh[3][lane]);
  __syncthreads();
  if (wave == 0) Lsh[0][lane] = li_w0;           // safe: only wave0 touches Lsh now
  if (quarter == 2){
    #pragma unroll
    for (int t = 0; t < 4; ++t){
      const int qi = t >> 1, ci = t & 1;
      #pragma unroll
      for (int rg = 0; rg < 16; ++rg){
        int row = qi * 32 + (rg & 3) + 8 * (rg >> 2) + 4 * h32;
        Osh[row][wv * 64 + ci * 32 + m32] += acc[t][rg];
      }
    }
  }
  __syncthreads();
  if (quarter == 1){
    #pragma unroll
    for (int t = 0; t < 4; ++t){
      const int qi = t >> 1, ci = t & 1;
      #pragma unroll
      for (int rg = 0; rg < 16; ++rg){
        int row = qi * 32 + (rg & 3) + 8 * (rg >> 2) + 4 * h32;
        Osh[row][wv * 64 + ci * 32 + m32] += acc[t][rg];
      }
    }
  }
  __syncthreads();
  // quarter 0 merges, scales, writes back to Osh
  if (quarter == 0){
    #pragma unroll
    for (int t = 0; t < 4; ++t){
      const int qi = t >> 1, ci = t & 1;
      #pragma unroll
      for (int rg = 0; rg < 16; ++rg){
        int row = qi * 32 + (rg & 3) + 8 * (rg >> 2) + 4 * h32;
        int col = wv * 64 + ci * 32 + m32;
        Osh[row][col] = (acc[t][rg] + Osh[row][col]) * Lsh[0][row];
      }
    }
  }
  __syncthreads();
  // coalesced: out = Osh + x
  const size_t base = ((size_t)(b * 4096) + q0) * 256;
  const float4* xs = (const float4*)(x + base);
  float4* od = (float4*)(out + base);
  const float4* Of = (const float4*)&Osh[0][0];
  #pragma unroll
  for (int i = 0; i < 4; ++i){
    int idx = i * 1024 + tid;
    float4 o = Of[idx], xv = xs[idx];
    o.x += xv.x; o.y += xv.y; o.z += xv.z; o.w += xv.w;
    od[idx] = o;
  }
}

extern "C" void kernel_launch(void* const* d_in, const int* in_sizes, int n_in,
                              void* d_out, int out_size, void* d_ws, size_t ws_size,
                              hipStream_t stream) {
  const float* x     = (const float*)d_in[0];
  const float* Wf    = (const float*)d_in[1];
  const float* Wg    = (const float*)d_in[2];
  const float* Wh    = (const float*)d_in[3];
  const float* gamma = (const float*)d_in[4];
  float* out = (float*)d_out;

  u16* p = (u16*)d_ws;
  u16* Qg    = p;  p += 16384 * 32;               // 1 MB
  u16* Kg    = p;  p += 16384 * 32;               // 1 MB
  u16* Vfrag = p;  p += 4 * 64 * 256 * 64;        // 8 MB, fragment-major
  u16* Wfrag = p;  p += 20 * 8 * 64 * 8;          // 160 KB, fragment-major

  prep_kernel<<<20, 512, 0, stream>>>(Wf, Wg, Wh, Wfrag);
  proj_kernel<<<256, 512, 0, stream>>>(x, Wfrag, Qg, Kg, Vfrag);
  flash_kernel<<<256, 1024, 0, stream>>>(Qg, Kg, Vfrag, x, gamma, out);
}

// Round 3
// 149.238 us; speedup vs baseline: 1.5611x; 1.5611x over previous
//
#include <hip/hip_runtime.h>
#include <hip/hip_bf16.h>

typedef __bf16 bf16x8 __attribute__((ext_vector_type(8)));
typedef float f32x4 __attribute__((ext_vector_type(4)));
typedef float f32x16 __attribute__((ext_vector_type(16)));
typedef unsigned short u16;
typedef unsigned int u32;

__device__ __forceinline__ u16 f2bf_rne(float f){
  union { float f; u32 u; } v; v.f = f;
  u32 r = v.u + 0x7fffu + ((v.u >> 16) & 1u);
  return (u16)(r >> 16);
}
// pack hi16(a)|hi16(b)<<16 in ONE v_perm_b32 (truncation; P feeds attention weights)
__device__ __forceinline__ u32 pack2(float a, float b){
  return __builtin_amdgcn_perm(__float_as_uint(a), __float_as_uint(b), 0x03020706u);
}
// workgroup barrier WITHOUT vmcnt drain (LDS visibility only): in-flight global
// loads (K/V register prefetches) ride through; compiler vmcnt-waits at use.
#define BARRIER_LGKM() asm volatile("s_waitcnt lgkmcnt(0)\n\ts_barrier" ::: "memory")

// ------------- prep: Wfrag = [Wh|Wf|Wg]^T in MFMA B-fragment order -------------
// Wfrag[cc(20)][kk(8)][lane(64)][j(8)] bf16; lane=(quad,L):
//   element = Wcat[k = kk*32 + quad*8 + j][n = cc*16 + L]
__global__ __launch_bounds__(512) void prep_kernel(
    const float* __restrict__ Wf, const float* __restrict__ Wg,
    const float* __restrict__ Wh, u16* __restrict__ Wfrag){
  const int cc = blockIdx.x;             // 20
  const int t = threadIdx.x;             // 512 = kk(8) x lane(64)
  const int kk = t >> 6, lane = t & 63;
  const int L = lane & 15, quad = lane >> 4;
  const int n = cc * 16 + L;
  u32 pk[4];
  #pragma unroll
  for (int j2 = 0; j2 < 4; ++j2){
    float v[2];
    #pragma unroll
    for (int h = 0; h < 2; ++h){
      int k = kk * 32 + quad * 8 + j2 * 2 + h;
      if (n < 256)      v[h] = Wh[k * 256 + n];
      else if (n < 288) v[h] = Wf[k * 32 + (n - 256)];
      else              v[h] = Wg[k * 32 + (n - 288)];
    }
    pk[j2] = (u32)f2bf_rne(v[0]) | ((u32)f2bf_rne(v[1]) << 16);
  }
  uint4* dst = (uint4*)(Wfrag + ((size_t)(cc * 8 + kk) * 64 + lane) * 8);
  *dst = make_uint4(pk[0], pk[1], pk[2], pk[3]);
}

// ---------------- projection: h/f/g via MFMA, 512 thr / 8 waves ----------------
// Qg pre-scaled by log2(e). V emitted fragment-major per 64-row group:
// Vfrag[g64][p_hi(8)][c(256)][j(8)], p = ((tn&15)<<2)|(tn>>4).
__global__ __launch_bounds__(512) void proj_kernel(
    const float* __restrict__ x, const u16* __restrict__ Wfrag,
    u16* __restrict__ Qg, u16* __restrict__ Kg, u16* __restrict__ Vfrag)
{
  __shared__ __align__(16) u16 smem[256 * 72];   // 36 KB, two phases
  u16 (*xb)[264] = (u16(*)[264])smem;
  u16 (*Vr)[72]  = (u16(*)[72])smem;

  const int tid = threadIdx.x;
  const int lane = tid & 63, wave = tid >> 6;
  const int L = lane & 15, quad = lane >> 4;
  const int rowgrp = wave >> 1, colhalf = wave & 1;
  const int n0 = blockIdx.x * 64;

  const float4* xsrc = (const float4*)(x + (size_t)n0 * 256);
  #pragma unroll
  for (int j = 0; j < 8; ++j){
    int idx = j * 512 + tid;
    int row = idx >> 6, col4 = idx & 63;
    float4 v = xsrc[idx];
    u32 p0 = (u32)f2bf_rne(v.x) | ((u32)f2bf_rne(v.y) << 16);
    u32 p1 = (u32)f2bf_rne(v.z) | ((u32)f2bf_rne(v.w) << 16);
    *(uint2*)&xb[row][col4 * 4] = make_uint2(p0, p1);
  }
  __syncthreads();

  f32x4 acc[10];
  #pragma unroll
  for (int cc = 0; cc < 10; ++cc) acc[cc] = (f32x4){0.f, 0.f, 0.f, 0.f};

  #pragma unroll
  for (int kk = 0; kk < 8; ++kk){
    bf16x8 a = *(const bf16x8*)&xb[rowgrp * 16 + L][kk * 32 + quad * 8];
    #pragma unroll
    for (int cc = 0; cc < 10; ++cc){
      int ccg = colhalf * 10 + cc;
      bf16x8 bfr = *(const bf16x8*)(Wfrag + ((size_t)(ccg * 8 + kk) * 64 + lane) * 8);
      acc[cc] = __builtin_amdgcn_mfma_f32_16x16x32_bf16(a, bfr, acc[cc], 0, 0, 0);
    }
  }

  if (colhalf){
    #pragma unroll
    for (int cc = 6; cc < 10; ++cc){
      int ccg = 10 + cc;                                  // 16..19
      u16* dst = (ccg < 18) ? Kg : Qg;                    // K = f, Q = g
      float sc = (ccg < 18) ? 1.0f : 1.44269504088896f;
      int c = (ccg & 1) * 16 + L;
      #pragma unroll
      for (int r = 0; r < 4; ++r){
        int row = n0 + rowgrp * 16 + quad * 4 + r;
        dst[(size_t)row * 32 + c] = f2bf_rne(acc[cc][r] * sc);
      }
    }
  }

  __syncthreads();   // xb consumed; reuse smem as Vr

  {
    const int cmax = colhalf ? 6 : 10;
    for (int cc = 0; cc < cmax; ++cc){
      int ccg = colhalf * 10 + cc;
      int c = ccg * 16 + L;
      #pragma unroll
      for (int r = 0; r < 4; ++r){
        int tn = rowgrp * 16 + quad * 4 + r;
        int p  = ((tn & 15) << 2) | (tn >> 4);
        Vr[c][p] = f2bf_rne(acc[cc][r]);
      }
    }
  }
  __syncthreads();

  u16* Vblk = Vfrag + (size_t)blockIdx.x * (256 * 64);
  #pragma unroll
  for (int i = 0; i < 4; ++i){
    int idx = i * 512 + tid;
    *(uint4*)(Vblk + (size_t)idx * 8) = *(const uint4*)&Vr[idx & 255][(idx >> 8) * 8];
  }
}

// ------- flash: q-tile 64, 12 waves = 3 internal k-thirds, fused epilogue ------
// grid 256 x 768 thr, 1 block/CU, 12 waves/CU = 3 waves/SIMD.
// WHY 768: R0 (512 thr, 2 waves/SIMD) was latency-bound (both pipes <30%,
// occ 18%); R2 (1024 thr) forced the 128-reg/wave budget and SPILLED
// (VGPR 64 + WRITE_SIZE 298MB scratch). This structure needs ~148 regs/wave
// (84 VGPR + 64 AGPR acc): fits the 3-wave/SIMD budget (170), not the 4-wave
// (128). So 3/SIMD is the max spill-free occupancy -> k split in thirds.
// third = wave>>2 sweeps nt tiles (22/21/21) from g0 (0/22/43); wv = wave&3.
// Hot-loop body is byte-identical to R0 (QK 4xMFMA -> exp2/pack -> P store ->
// barrier -> PV 16xMFMA, kc/vfc prefetched). Uneven trip counts are equalized
// by barrier-padding AFTER the loop so every wave hits exactly 22 barriers.
// K/V traffic per block UNCHANGED (each third reads only its own k-range).
// Epilogue: 3 thirds merge sequentially via LDS Osh (overlays Plds), l via Lsh.
__global__ __launch_bounds__(768) void flash_kernel(
    const u16* __restrict__ Qg, const u16* __restrict__ Kg, const u16* __restrict__ Vfrag,
    const float* __restrict__ x, const float* __restrict__ gamma, float* __restrict__ out)
{
  constexpr float SH = -92.33248261689366f;      // -64*log2(e); s already log2-scaled
  __shared__ __align__(16) char smem[65536];     // Plds 55296 B overlaid by Osh 64 KB
  u16 (*Plds)[2][64][72] = (u16 (*)[2][64][72])smem;  // [third][buf][row][72]
  float (*Osh)[256] = (float (*)[256])smem;
  __shared__ float Lsh[3][64];

  const int tid = threadIdx.x, lane = tid & 63, wave = tid >> 6;   // wave 0..11
  const int L = lane & 15, quad = lane >> 4;
  const int m32 = lane & 31, h32 = lane >> 5;
  const int third = wave >> 2, wv = wave & 3;

  // XCD swizzle: id&7 -> XCD; 2 XCDs per batch (V+K+Q working set ~2.5MB < 4MB L2)
  const int id = blockIdx.x;                     // 0..255
  const int xcd = id & 7;
  const int b = xcd >> 1;
  const int qt = (xcd & 1) * 32 + (id >> 3);     // 0..63
  const int q0 = qt * 64;

  const u16* Qb = Qg + (size_t)(b * 4096) * 32;
  const u16* Kb = Kg + (size_t)(b * 4096) * 32;
  const u16* Vb = Vfrag + (size_t)b * (64 * 256 * 64);
  const float gm = gamma[0];

  const int nt = (third == 0) ? 22 : 21;         // 22+21+21 = 64 k-tiles
  const int g0 = (third == 0) ? 0 : (22 + (third - 1) * 21);

  bf16x8 qa = *(const bf16x8*)(Qb + (size_t)(q0 + wv * 16 + L) * 32 + quad * 8);
  const u16* kp0 = Kb + (size_t)(g0 * 64 + L) * 32 + quad * 8;
  bf16x8 kc0 = *(const bf16x8*)(kp0);
  bf16x8 kc1 = *(const bf16x8*)(kp0 + 512);
  bf16x8 kc2 = *(const bf16x8*)(kp0 + 1024);
  bf16x8 kc3 = *(const bf16x8*)(kp0 + 1536);

  bf16x8 vfc[8];
  {
    const u16* Vt = Vb + (size_t)g0 * (256 * 64);
    #pragma unroll
    for (int ks = 0; ks < 4; ++ks){
      const u16* vrow = Vt + (size_t)((ks * 2 + h32) * 256 + wv * 64 + m32) * 8;
      vfc[ks * 2]     = *(const bf16x8*)(vrow);
      vfc[ks * 2 + 1] = *(const bf16x8*)(vrow + 32 * 8);
    }
  }

  f32x16 acc[4];                                  // [qi*2+ci]: 64q x 64c
  #pragma unroll
  for (int t = 0; t < 4; ++t)
    #pragma unroll
    for (int i = 0; i < 16; ++i) acc[t][i] = 0.f;
  float lsum[4] = {0.f, 0.f, 0.f, 0.f};
  const f32x4 zero = (f32x4){0.f, 0.f, 0.f, 0.f};

  for (int kt = 0; kt < nt; ++kt){
    const int g = g0 + kt;
    u16 (*Pw)[72] = Plds[third][kt & 1];

    // ---- QK^T from registers (s log2-scaled via Qg) ----
    f32x4 s0 = __builtin_amdgcn_mfma_f32_16x16x32_bf16(qa, kc0, zero, 0, 0, 0);
    f32x4 s1 = __builtin_amdgcn_mfma_f32_16x16x32_bf16(qa, kc1, zero, 0, 0, 0);
    f32x4 s2 = __builtin_amdgcn_mfma_f32_16x16x32_bf16(qa, kc2, zero, 0, 0, 0);
    f32x4 s3 = __builtin_amdgcn_mfma_f32_16x16x32_bf16(qa, kc3, zero, 0, 0, 0);

    // ---- kc reload for kt+1 (window = exp + barrier + PV) ----
    if (kt < nt - 1){
      const u16* kpn = Kb + (size_t)((g + 1) * 64 + L) * 32 + quad * 8;
      kc0 = *(const bf16x8*)(kpn);
      kc1 = *(const bf16x8*)(kpn + 512);
      kc2 = *(const bf16x8*)(kpn + 1024);
      kc3 = *(const bf16x8*)(kpn + 1536);
    }

    // ---- p = exp2(s+SH); lsum; packed P store (col' = L*4+j) ----
    #pragma unroll
    for (int r = 0; r < 4; ++r){
      float p0 = __builtin_amdgcn_exp2f(s0[r] + SH);
      float p1 = __builtin_amdgcn_exp2f(s1[r] + SH);
      float p2 = __builtin_amdgcn_exp2f(s2[r] + SH);
      float p3 = __builtin_amdgcn_exp2f(s3[r] + SH);
      lsum[r] += (p0 + p1) + (p2 + p3);
      *(uint2*)&Pw[wv * 16 + quad * 4 + r][L * 4] =
          make_uint2(pack2(p0, p1), pack2(p2, p3));
    }

    BARRIER_LGKM();   // P visible; global prefetches ride through

    // ---- O += P V : af from own third's Plds, vf already in registers ----
    #pragma unroll
    for (int ks = 0; ks < 4; ++ks){
      bf16x8 af0 = *(const bf16x8*)&Pw[m32][ks * 16 + h32 * 8];
      bf16x8 af1 = *(const bf16x8*)&Pw[32 + m32][ks * 16 + h32 * 8];
      acc[0] = __builtin_amdgcn_mfma_f32_32x32x16_bf16(af0, vfc[ks*2],   acc[0], 0, 0, 0);
      acc[1] = __builtin_amdgcn_mfma_f32_32x32x16_bf16(af0, vfc[ks*2+1], acc[1], 0, 0, 0);
      acc[2] = __builtin_amdgcn_mfma_f32_32x32x16_bf16(af1, vfc[ks*2],   acc[2], 0, 0, 0);
      acc[3] = __builtin_amdgcn_mfma_f32_32x32x16_bf16(af1, vfc[ks*2+1], acc[3], 0, 0, 0);
    }

    // ---- vf loads for kt+1 into the same regs (consumed after next barrier) ----
    if (kt < nt - 1){
      const u16* Vn = Vb + (size_t)(g + 1) * (256 * 64);
      #pragma unroll
      for (int ks = 0; ks < 4; ++ks){
        const u16* vrow = Vn + (size_t)((ks * 2 + h32) * 256 + wv * 64 + m32) * 8;
        vfc[ks * 2]     = *(const bf16x8*)(vrow);
        vfc[ks * 2 + 1] = *(const bf16x8*)(vrow + 32 * 8);
      }
    }
    // no end barrier: per-third Plds double-buffered; reuse gated by next barrier
  }
  // equalize barrier counts across thirds (22/21/21 trip counts -> 22 each)
  for (int e = nt; e < 22; ++e) BARRIER_LGKM();

  // ================= fused epilogue (3-way k-third merge) =================
  // l: reduce 16 partial lanes per (quad,r); rows wv*16+quad*4+r of this third
  #pragma unroll
  for (int r = 0; r < 4; ++r){
    lsum[r] += __shfl_xor(lsum[r], 1);
    lsum[r] += __shfl_xor(lsum[r], 2);
    lsum[r] += __shfl_xor(lsum[r], 4);
    lsum[r] += __shfl_xor(lsum[r], 8);
  }
  if (L == 0){
    #pragma unroll
    for (int r = 0; r < 4; ++r) Lsh[third][wv * 16 + quad * 4 + r] = lsum[r];
  }

  BARRIER_LGKM();   // all PV ds-reads retired (per-wave lgkm drain) + Lsh visible

  // third 2 deposits its accumulator into Osh (fp32); wave 0 computes scale
  if (third == 2){
    #pragma unroll
    for (int t = 0; t < 4; ++t){
      const int qi = t >> 1, ci = t & 1;
      #pragma unroll
      for (int rg = 0; rg < 16; ++rg){
        int row = qi * 32 + (rg & 3) + 8 * (rg >> 2) + 4 * h32;   // 32x32 C-layout
        Osh[row][wv * 64 + ci * 32 + m32] = acc[t][rg];
      }
    }
  }
  float li_w0 = 0.f;
  if (wave == 0)
    li_w0 = gm / (Lsh[0][lane] + Lsh[1][lane] + Lsh[2][lane]);
  __syncthreads();
  if (wave == 0) Lsh[0][lane] = li_w0;           // safe: only wave0 touches Lsh now
  if (third == 1){
    #pragma unroll
    for (int t = 0; t < 4; ++t){
      const int qi = t >> 1, ci = t & 1;
      #pragma unroll
      for (int rg = 0; rg < 16; ++rg){
        int row = qi * 32 + (rg & 3) + 8 * (rg >> 2) + 4 * h32;
        Osh[row][wv * 64 + ci * 32 + m32] += acc[t][rg];
      }
    }
  }
  __syncthreads();
  // third 0 merges, scales, writes back to Osh
  if (third == 0){
    #pragma unroll
    for (int t = 0; t < 4; ++t){
      const int qi = t >> 1, ci = t & 1;
      #pragma unroll
      for (int rg = 0; rg < 16; ++rg){
        int row = qi * 32 + (rg & 3) + 8 * (rg >> 2) + 4 * h32;
        int col = wv * 64 + ci * 32 + m32;
        Osh[row][col] = (acc[t][rg] + Osh[row][col]) * Lsh[0][row];
      }
    }
  }
  __syncthreads();
  // coalesced: out = Osh + x  (4096 float4 over 768 threads)
  const size_t base = ((size_t)(b * 4096) + q0) * 256;
  const float4* xs = (const float4*)(x + base);
  float4* od = (float4*)(out + base);
  const float4* Of = (const float4*)&Osh[0][0];
  #pragma unroll
  for (int i = 0; i < 6; ++i){
    int idx = i * 768 + tid;
    if (idx < 4096){
      float4 o = Of[idx], xv = xs[idx];
      o.x += xv.x; o.y += xv.y; o.z += xv.z; o.w += xv.w;
      od[idx] = o;
    }
  }
}

extern "C" void kernel_launch(void* const* d_in, const int* in_sizes, int n_in,
                              void* d_out, int out_size, void* d_ws, size_t ws_size,
                              hipStream_t stream) {
  const float* x     = (const float*)d_in[0];
  const float* Wf    = (const float*)d_in[1];
  const float* Wg    = (const float*)d_in[2];
  const float* Wh    = (const float*)d_in[3];
  const float* gamma = (const float*)d_in[4];
  float* out = (float*)d_out;

  u16* p = (u16*)d_ws;
  u16* Qg    = p;  p += 16384 * 32;               // 1 MB
  u16* Kg    = p;  p += 16384 * 32;               // 1 MB
  u16* Vfrag = p;  p += 4 * 64 * 256 * 64;        // 8 MB, fragment-major
  u16* Wfrag = p;  p += 20 * 8 * 64 * 8;          // 160 KB, fragment-major

  prep_kernel<<<20, 512, 0, stream>>>(Wf, Wg, Wh, Wfrag);
  proj_kernel<<<256, 512, 0, stream>>>(x, Wfrag, Qg, Kg, Vfrag);
  flash_kernel<<<256, 768, 0, stream>>>(Qg, Kg, Vfrag, x, gamma, out);
}